// Round 6
// baseline (1135.131 us; speedup 1.0000x reference)
//
#include <hip/hip_runtime.h>
#include <hip/hip_bf16.h>
#include <math.h>

// DualMAR: 2-layer weighted GCN over 100K nodes / 3.2M edges + code/visit
// attention + MLP decoder.
// R5: fill/hist process 4 edges/thread (4 independent atomic->store chains
// = 4x MLP; R4 counters showed fill latency-bound: VALUBusy 0.37%, 0.9 TB/s)
// + nontemporal scatter stores. agg/GEMM/attention unchanged from R4.

#define D 256
#define BPAT 64
#define VIS 50
#define CODES 64
#define NEG_INF -1e9f
#define MPAD 100096   // 782 * 128 (NN=100000 padded to BM=128)

typedef unsigned short ushort_t;
typedef short short8 __attribute__((ext_vector_type(8)));
typedef float f32x4 __attribute__((ext_vector_type(4)));

__device__ __forceinline__ float blo(unsigned u) { return __uint_as_float(u << 16); }
__device__ __forceinline__ float bhi(unsigned u) { return __uint_as_float(u & 0xffff0000u); }
__device__ __forceinline__ float bf2f(ushort_t u) { return __uint_as_float((unsigned)u << 16); }
__device__ __forceinline__ ushort_t f2bfu(float f) {
    __hip_bfloat16 h = __float2bfloat16(f);
    return *reinterpret_cast<ushort_t*>(&h);
}
__device__ __forceinline__ unsigned pack2(float a, float b) {
    return (unsigned)f2bfu(a) | ((unsigned)f2bfu(b) << 16);
}

// ---------------- CSR build ----------------

// 4 edges/thread: int4 dst load, 4 independent atomics in flight
__global__ __launch_bounds__(256) void hist_kernel(
    const int* __restrict__ ei, int* __restrict__ counts, int ne) {
    int e = (blockIdx.x * blockDim.x + threadIdx.x) * 4;
    if (e + 4 <= ne) {
        int4 d = *(const int4*)(ei + (size_t)ne + e);
        atomicAdd(&counts[d.x], 1);
        atomicAdd(&counts[d.y], 1);
        atomicAdd(&counts[d.z], 1);
        atomicAdd(&counts[d.w], 1);
    } else {
        for (int j = e; j < ne; ++j) atomicAdd(&counts[ei[(size_t)ne + j]], 1);
    }
}

__global__ __launch_bounds__(1024) void block_sum_kernel(
    const int* __restrict__ counts, int* __restrict__ bsum, int n) {
    __shared__ int wsum[16];
    int tid = threadIdx.x, lane = tid & 63, wid = tid >> 6;
    int i = blockIdx.x * 1024 + tid;
    int v = (i < n) ? counts[i] : 0;
    #pragma unroll
    for (int d = 32; d; d >>= 1) v += __shfl_xor(v, d, 64);
    if (lane == 0) wsum[wid] = v;
    __syncthreads();
    if (tid == 0) {
        int s = 0;
        #pragma unroll
        for (int w = 0; w < 16; ++w) s += wsum[w];
        bsum[blockIdx.x] = s;
    }
}

__global__ __launch_bounds__(64) void scan_bsum_kernel(int* __restrict__ bsum, int nb) {
    __shared__ int carry;
    int lane = threadIdx.x;
    if (lane == 0) carry = 0;
    __syncthreads();
    for (int base = 0; base < nb; base += 64) {
        int i = base + lane;
        int v = (i < nb) ? bsum[i] : 0;
        int x = v;
        #pragma unroll
        for (int d = 1; d < 64; d <<= 1) {
            int y = __shfl_up(x, (unsigned)d, 64);
            if (lane >= d) x += y;
        }
        int c = carry;
        if (i < nb) bsum[i] = c + x - v;   // exclusive
        __syncthreads();
        if (lane == 63) carry = c + x;
        __syncthreads();
    }
}

__global__ __launch_bounds__(1024) void block_scan_kernel(
    int* __restrict__ counts, const int* __restrict__ bsum,
    int* __restrict__ rp, int n) {
    __shared__ int wsum[16];
    int tid = threadIdx.x, lane = tid & 63, wid = tid >> 6;
    int i = blockIdx.x * 1024 + tid;
    int v = (i < n) ? counts[i] : 0;
    int x = v;
    #pragma unroll
    for (int d = 1; d < 64; d <<= 1) {
        int y = __shfl_up(x, (unsigned)d, 64);
        if (lane >= d) x += y;
    }
    if (lane == 63) wsum[wid] = x;
    __syncthreads();
    int off = bsum[blockIdx.x];
    #pragma unroll
    for (int w = 0; w < 16; ++w) off += (w < wid) ? wsum[w] : 0;
    if (i < n) {
        int incl = off + x;
        rp[i + 1] = incl;
        counts[i] = incl - v;   // exclusive prefix = fill cursor
    }
    if (i == 0) rp[0] = 0;
}

// 4 edges/thread: coalesced int4/float4 reads, 4 independent atomic->nt-store
// chains in flight per thread.
__device__ __forceinline__ void fill_one(int src, int dst, float w,
                                         int* cursor, uint2* ep) {
    int pos = atomicAdd(&cursor[dst], 1);
    unsigned long long pv =
        ((unsigned long long)__float_as_uint(w) << 32) | (unsigned)src;
    __builtin_nontemporal_store(pv, (unsigned long long*)&ep[pos]);
}

__global__ __launch_bounds__(256) void fill_kernel(
    const int* __restrict__ ei, const float* __restrict__ ew,
    int* __restrict__ cursor, uint2* __restrict__ ep, int ne) {
    int e = (blockIdx.x * blockDim.x + threadIdx.x) * 4;
    if (e + 4 <= ne) {
        int4 s = *(const int4*)(ei + e);
        int4 d = *(const int4*)(ei + (size_t)ne + e);
        float4 w = *(const float4*)(ew + e);
        fill_one(s.x, d.x, w.x, cursor, ep);
        fill_one(s.y, d.y, w.y, cursor, ep);
        fill_one(s.z, d.z, w.z, cursor, ep);
        fill_one(s.w, d.w, w.w, cursor, ep);
    } else {
        for (int j = e; j < ne; ++j)
            fill_one(ei[j], ei[(size_t)ne + j], ew[j], cursor, ep);
    }
}

// ---------------- fp32 -> bf16 node table (pad rows zeroed) ----------------
__global__ void cvt_node_kernel(const float* __restrict__ in, ushort_t* __restrict__ out,
                                long n_valid, long n_total) {
    long g = (long)blockIdx.x * blockDim.x + threadIdx.x;
    long ng = n_total >> 2;
    for (long i = g; i < ng; i += (long)gridDim.x * blockDim.x) {
        long e = i << 2;
        uint2 o;
        if (e < n_valid) {
            float4 v = ((const float4*)in)[i];
            o.x = pack2(v.x, v.y);
            o.y = pack2(v.z, v.w);
        } else {
            o.x = 0u; o.y = 0u;
        }
        ((uint2*)out)[i] = o;
    }
}

// ---------------- weight transpose: W[k][n] fp32 -> Wt[n][k] bf16 (256x256) --
__global__ __launch_bounds__(256) void transpose_w_kernel(
    const float* __restrict__ W, ushort_t* __restrict__ Wt) {
    __shared__ float t[32][33];
    int bx = blockIdx.x * 32;   // n base
    int by = blockIdx.y * 32;   // k base
    int lx = threadIdx.x & 31, ly = threadIdx.x >> 5;   // 32 x 8
    #pragma unroll
    for (int i = 0; i < 32; i += 8)
        t[ly + i][lx] = W[(size_t)(by + ly + i) * 256 + bx + lx];
    __syncthreads();
    #pragma unroll
    for (int i = 0; i < 32; i += 8)
        Wt[(size_t)(bx + ly + i) * 256 + by + lx] = f2bfu(t[lx][ly + i]);
}

// ---------------- weighted aggregation over bf16 rows ----------------
// One wave per dst row, two 32-lane halves gather different edges with
// 16B/lane uint4 loads; 8-edge unrolled main loop.
__device__ __forceinline__ void acc8(float* a, uint4 v, float w) {
    a[0] += w * blo(v.x); a[1] += w * bhi(v.x);
    a[2] += w * blo(v.y); a[3] += w * bhi(v.y);
    a[4] += w * blo(v.z); a[5] += w * bhi(v.z);
    a[6] += w * blo(v.w); a[7] += w * bhi(v.w);
}

__global__ __launch_bounds__(256) void agg_bf16_kernel(
    const ushort_t* __restrict__ x, const int* __restrict__ rp,
    const uint2* __restrict__ ep, ushort_t* __restrict__ out, int n) {
    int wv = (int)(((size_t)blockIdx.x * blockDim.x + threadIdx.x) >> 6);
    int lane = threadIdx.x & 63;
    if (wv >= n) return;
    int half = lane >> 5;
    int l32 = lane & 31;
    int beg = rp[wv], end = rp[wv + 1];
    float a[8] = {};
    int e = beg;
    for (; e + 8 <= end; e += 8) {
        uint2 p0 = ep[e + half];
        uint2 p1 = ep[e + 2 + half];
        uint2 p2 = ep[e + 4 + half];
        uint2 p3 = ep[e + 6 + half];
        uint4 v0 = ((const uint4*)(x + (size_t)p0.x * D))[l32];
        uint4 v1 = ((const uint4*)(x + (size_t)p1.x * D))[l32];
        uint4 v2 = ((const uint4*)(x + (size_t)p2.x * D))[l32];
        uint4 v3 = ((const uint4*)(x + (size_t)p3.x * D))[l32];
        acc8(a, v0, __uint_as_float(p0.y));
        acc8(a, v1, __uint_as_float(p1.y));
        acc8(a, v2, __uint_as_float(p2.y));
        acc8(a, v3, __uint_as_float(p3.y));
    }
    for (; e + 2 <= end; e += 2) {
        uint2 p0 = ep[e + half];
        uint4 v0 = ((const uint4*)(x + (size_t)p0.x * D))[l32];
        acc8(a, v0, __uint_as_float(p0.y));
    }
    if (e < end) {   // odd tail: both halves read the same row, upper weight 0
        uint2 p0 = ep[e];
        uint4 v0 = ((const uint4*)(x + (size_t)p0.x * D))[l32];
        acc8(a, v0, half ? 0.f : __uint_as_float(p0.y));
    }
    #pragma unroll
    for (int j = 0; j < 8; ++j) a[j] += __shfl_xor(a[j], 32, 64);
    if (half == 0) {
        uint4 o;
        o.x = pack2(a[0], a[1]); o.y = pack2(a[2], a[3]);
        o.z = pack2(a[4], a[5]); o.w = pack2(a[6], a[7]);
        ((uint4*)(out + (size_t)wv * D))[l32] = o;
    }
}

// ---------------- bf16 MFMA GEMM: 128x256 tile, BK=32, 8 waves (512 thr) ----
// A bf16 row-major [*,256]; Wt = W^T bf16. LDS XOR-swizzle c^=((row>>1)&3).
// MODE 0: relu(A@W+bias) -> bf16 out
// MODE 1: A@W+bias       -> bf16 out
// MODE 2: tout[row] = sum_col tanh((A@W)[row,col]) * u[col]  (no out store)
template<int MODE>
__global__ __launch_bounds__(512) void mfma_gemm_kernel(
    const ushort_t* __restrict__ A, const ushort_t* __restrict__ Wt,
    const float* __restrict__ bias, ushort_t* __restrict__ out,
    const float* __restrict__ u, float* __restrict__ tout, int mvalid) {
    __shared__ __align__(16) ushort_t As[128 * 32];
    __shared__ __align__(16) ushort_t Bs[256 * 32];
    __shared__ float s_t[128];
    const int tid = threadIdx.x;
    const int lane = tid & 63;
    const int wv = tid >> 6;           // 0..7
    const int wr = wv >> 2, wc = wv & 3;
    const size_t brow = (size_t)blockIdx.x * 128;

    const int ra = tid >> 2, ca = tid & 3;
    const int rb1 = ra + 128;
    const int csa = ca ^ ((ra >> 1) & 3);
    const ushort_t* gA  = A  + (brow + ra) * 256 + ca * 8;
    const ushort_t* gB0 = Wt + (size_t)ra  * 256 + ca * 8;
    const ushort_t* gB1 = Wt + (size_t)rb1 * 256 + ca * 8;
    ushort_t* lA  = As + ra * 32 + csa * 8;
    ushort_t* lB0 = Bs + ra * 32 + csa * 8;
    ushort_t* lB1 = Bs + rb1 * 32 + csa * 8;

    const int g = lane >> 4, rl = lane & 15;
    int aoff[4], boff[4];
    #pragma unroll
    for (int m = 0; m < 4; ++m) {
        int row = wr * 64 + m * 16 + rl;
        aoff[m] = row * 32 + (g ^ ((row >> 1) & 3)) * 8;
    }
    #pragma unroll
    for (int n = 0; n < 4; ++n) {
        int row = wc * 64 + n * 16 + rl;
        boff[n] = row * 32 + (g ^ ((row >> 1) & 3)) * 8;
    }

    if (MODE == 2 && tid < 128) s_t[tid] = 0.f;

    f32x4 acc[4][4] = {};
    uint4 va  = *(const uint4*)gA;
    uint4 vb0 = *(const uint4*)gB0;
    uint4 vb1 = *(const uint4*)gB1;

    for (int ks = 0; ks < 8; ++ks) {
        *(uint4*)lA = va; *(uint4*)lB0 = vb0; *(uint4*)lB1 = vb1;
        __syncthreads();
        if (ks < 7) {
            int k0 = (ks + 1) * 32;
            va  = *(const uint4*)(gA + k0);
            vb0 = *(const uint4*)(gB0 + k0);
            vb1 = *(const uint4*)(gB1 + k0);
        }
        short8 af[4], bfv[4];
        #pragma unroll
        for (int m = 0; m < 4; ++m) af[m] = *(const short8*)(As + aoff[m]);
        #pragma unroll
        for (int n = 0; n < 4; ++n) bfv[n] = *(const short8*)(Bs + boff[n]);
        #pragma unroll
        for (int m = 0; m < 4; ++m)
            #pragma unroll
            for (int n = 0; n < 4; ++n)
                acc[m][n] = __builtin_amdgcn_mfma_f32_16x16x32_bf16(
                    af[m], bfv[n], acc[m][n], 0, 0, 0);
        __syncthreads();
    }

    if (MODE == 2) {
        float uvv[4];
        #pragma unroll
        for (int n = 0; n < 4; ++n) uvv[n] = u[wc * 64 + n * 16 + rl];
        #pragma unroll
        for (int m = 0; m < 4; ++m) {
            #pragma unroll
            for (int r = 0; r < 4; ++r) {
                float v = 0.f;
                #pragma unroll
                for (int n = 0; n < 4; ++n) v += tanhf(acc[m][n][r]) * uvv[n];
                v += __shfl_xor(v, 1, 64);
                v += __shfl_xor(v, 2, 64);
                v += __shfl_xor(v, 4, 64);
                v += __shfl_xor(v, 8, 64);
                if (rl == 0) atomicAdd(&s_t[wr * 64 + m * 16 + g * 4 + r], v);
            }
        }
        __syncthreads();
        if (tid < 128 && brow + tid < (size_t)mvalid) tout[brow + tid] = s_t[tid];
    } else {
        #pragma unroll
        for (int m = 0; m < 4; ++m) {
            #pragma unroll
            for (int r = 0; r < 4; ++r) {
                size_t row = brow + wr * 64 + m * 16 + g * 4 + r;
                #pragma unroll
                for (int n = 0; n < 4; ++n) {
                    int col = wc * 64 + n * 16 + rl;
                    float v = acc[m][n][r] + bias[col];
                    if (MODE == 0) v = fmaxf(v, 0.f);
                    out[row * 256 + col] = f2bfu(v);
                }
            }
        }
    }
}

// ---------------- code attention: one block per (b,v), emb bf16 -> vemb bf16
__global__ __launch_bounds__(256) void code_attn_kernel(
    const int* __restrict__ codes, const float* __restrict__ t,
    const ushort_t* __restrict__ emb, ushort_t* __restrict__ vembB,
    int* __restrict__ vmask) {
    int bv = blockIdx.x;
    int tid = threadIdx.x;
    __shared__ int s_codes[CODES];
    __shared__ float s_av[CODES];
    __shared__ int s_valid;
    if (tid < 64) {
        int c = codes[(size_t)bv * CODES + tid];
        s_codes[tid] = c;
        float e = (c > 0) ? t[c] : NEG_INF;
        float m = e;
        #pragma unroll
        for (int d = 32; d; d >>= 1) m = fmaxf(m, __shfl_xor(m, d, 64));
        float ex = expf(e - m);
        float s = ex;
        #pragma unroll
        for (int d = 32; d; d >>= 1) s += __shfl_xor(s, d, 64);
        s_av[tid] = ex / s;
        if (tid == 0) s_valid = (m > -1e8f) ? 1 : 0;
    }
    __syncthreads();
    float acc = 0.f;
    #pragma unroll 4
    for (int c = 0; c < CODES; ++c) {
        int node = s_codes[c];
        if (node > 0) acc += s_av[c] * bf2f(emb[(size_t)node * D + tid]);
    }
    int valid = s_valid;
    vembB[(size_t)bv * D + tid] = f2bfu(valid ? acc : 0.f);
    if (tid == 0) vmask[bv] = valid;
}

// per-patient: masked softmax over visit scores, pemb = sum ap * vemb
__global__ __launch_bounds__(256) void patient_kernel(
    const ushort_t* __restrict__ vembB, const float* __restrict__ epr,
    const int* __restrict__ vmask, float* __restrict__ pemb) {
    int b = blockIdx.x;
    int tid = threadIdx.x;
    __shared__ float s_ap[VIS];
    __shared__ int s_any;
    if (tid < 64) {
        float e = -3e38f;
        if (tid < VIS) e = vmask[b * VIS + tid] ? epr[b * VIS + tid] : NEG_INF;
        float m = e;
        #pragma unroll
        for (int d = 32; d; d >>= 1) m = fmaxf(m, __shfl_xor(m, d, 64));
        float ex = (tid < VIS) ? expf(e - m) : 0.f;
        float s = ex;
        #pragma unroll
        for (int d = 32; d; d >>= 1) s += __shfl_xor(s, d, 64);
        if (tid < VIS) s_ap[tid] = ex / s;
        if (tid == 0) s_any = (m > -1e8f) ? 1 : 0;
    }
    __syncthreads();
    float acc = 0.f;
    for (int v = 0; v < VIS; ++v)
        acc += s_ap[v] * bf2f(vembB[((size_t)b * VIS + v) * D + tid]);
    pemb[b * D + tid] = s_any ? acc : 0.f;
}

__global__ __launch_bounds__(256) void gemm_rowcol(
    const float* __restrict__ A, const float* __restrict__ W,
    const float* __restrict__ bias, float* __restrict__ C,
    int M, int N, int K, int act) {
    int row = blockIdx.x;
    int col = blockIdx.y * 256 + threadIdx.x;
    if (col >= N) return;
    const float* a = A + (size_t)row * K;
    float acc = bias ? bias[col] : 0.f;
    #pragma unroll 4
    for (int k = 0; k < K; ++k) acc = fmaf(a[k], W[(size_t)k * N + col], acc);
    if (act == 1) acc = fmaxf(acc, 0.f);
    C[(size_t)row * N + col] = acc;
}

extern "C" void kernel_launch(void* const* d_in, const int* in_sizes, int n_in,
                              void* d_out, int out_size, void* d_ws, size_t ws_size,
                              hipStream_t stream) {
    const int* edge_index    = (const int*)d_in[0];
    const float* edge_weight = (const float*)d_in[1];
    const int* codes         = (const int*)d_in[2];
    const float* node_emb    = (const float*)d_in[3];
    const float* W1 = (const float*)d_in[4];
    const float* b1 = (const float*)d_in[5];
    const float* W2 = (const float*)d_in[6];
    const float* b2 = (const float*)d_in[7];
    const float* Wv = (const float*)d_in[8];
    const float* uv = (const float*)d_in[9];
    const float* Wp = (const float*)d_in[10];
    const float* up = (const float*)d_in[11];
    const float* Wd1 = (const float*)d_in[12];
    const float* bd1 = (const float*)d_in[13];
    const float* Wd2 = (const float*)d_in[14];
    const float* bd2 = (const float*)d_in[15];
    const float* Wd3 = (const float*)d_in[16];
    const float* bd3 = (const float*)d_in[17];

    const int NE = in_sizes[1];          // 3,200,000
    const int NN = in_sizes[3] / D;      // 100,000

    char* ws = (char*)d_ws;
    size_t off = 0;
    auto alloc = [&](size_t bytes) -> void* {
        void* p = ws + off;
        off += (bytes + 255) & ~(size_t)255;
        return p;
    };
    ushort_t* nbf  = (ushort_t*)alloc((size_t)MPAD * D * 2);  // node table / h
    ushort_t* aggb = (ushort_t*)alloc((size_t)MPAD * D * 2);  // agg out
    ushort_t* embB = (ushort_t*)alloc((size_t)MPAD * D * 2);  // emb (bf16)
    uint2* epair  = (uint2*)alloc((size_t)NE * 8);            // (src, w) pairs
    int*   counts = (int*)  alloc((size_t)NN * 4);
    int*   rp     = (int*)  alloc((size_t)(NN + 1) * 4);
    int*   bsum   = (int*)  alloc(1024 * 4);
    ushort_t* W1t = (ushort_t*)alloc(256 * 256 * 2);
    ushort_t* W2t = (ushort_t*)alloc(256 * 256 * 2);
    ushort_t* Wvt = (ushort_t*)alloc(256 * 256 * 2);
    ushort_t* Wpt = (ushort_t*)alloc(256 * 256 * 2);
    float* tbuf  = (float*)alloc((size_t)NN * 4);
    ushort_t* vembB = (ushort_t*)alloc((size_t)BPAT * VIS * D * 2);
    int*   vmask = (int*)  alloc((size_t)BPAT * VIS * 4);
    float* epr   = (float*)alloc((size_t)BPAT * VIS * 4);
    float* pemb  = (float*)alloc((size_t)BPAT * D * 4);
    float* h1    = (float*)alloc((size_t)BPAT * 512 * 4);
    float* h2    = (float*)alloc((size_t)BPAT * D * 4);
    (void)ws_size; (void)n_in; (void)out_size;

    const int eb4 = (NE / 4 + 255) / 256;     // 4 edges/thread
    const int ab = NN / 4;                    // one wave/row, 4 waves/block
    const int nb = (NN + 1023) / 1024;

    // --- CSR build ---
    hipMemsetAsync(counts, 0, (size_t)NN * 4, stream);
    hist_kernel<<<eb4, 256, 0, stream>>>(edge_index, counts, NE);
    block_sum_kernel<<<nb, 1024, 0, stream>>>(counts, bsum, NN);
    scan_bsum_kernel<<<1, 64, 0, stream>>>(bsum, nb);
    block_scan_kernel<<<nb, 1024, 0, stream>>>(counts, bsum, rp, NN);
    fill_kernel<<<eb4, 256, 0, stream>>>(edge_index, edge_weight, counts, epair, NE);

    // --- bf16 conversions ---
    cvt_node_kernel<<<2048, 256, 0, stream>>>(node_emb, nbf, (long)NN * D, (long)MPAD * D);
    dim3 tg(8, 8);
    transpose_w_kernel<<<tg, 256, 0, stream>>>(W1, W1t);
    transpose_w_kernel<<<tg, 256, 0, stream>>>(W2, W2t);
    transpose_w_kernel<<<tg, 256, 0, stream>>>(Wv, Wvt);
    transpose_w_kernel<<<tg, 256, 0, stream>>>(Wp, Wpt);

    // --- GCN layer 1: h = relu(agg(x) @ W1 + b1) ---
    agg_bf16_kernel<<<ab, 256, 0, stream>>>(nbf, rp, epair, aggb, NN);
    mfma_gemm_kernel<0><<<MPAD / 128, 512, 0, stream>>>(
        aggb, W1t, b1, nbf, nullptr, nullptr, 0);

    // --- GCN layer 2: emb = agg(h) @ W2 + b2 ---
    agg_bf16_kernel<<<ab, 256, 0, stream>>>(nbf, rp, epair, aggb, NN);
    mfma_gemm_kernel<1><<<MPAD / 128, 512, 0, stream>>>(
        aggb, W2t, b2, embB, nullptr, nullptr, 0);

    // --- fused per-node code score: t = tanh(emb @ Wv) @ uv ---
    mfma_gemm_kernel<2><<<MPAD / 128, 512, 0, stream>>>(
        embB, Wvt, nullptr, nullptr, uv, tbuf, NN);

    // --- code attention -> vemb (bf16) ---
    code_attn_kernel<<<BPAT * VIS, 256, 0, stream>>>(codes, tbuf, embB, vembB, vmask);

    // --- fused visit score: ep = tanh(vemb @ Wp) @ up  (3200 = 25*128 rows) ---
    mfma_gemm_kernel<2><<<BPAT * VIS / 128, 512, 0, stream>>>(
        vembB, Wpt, nullptr, nullptr, up, epr, BPAT * VIS);

    // --- patient attention + decoder ---
    patient_kernel<<<BPAT, 256, 0, stream>>>(vembB, epr, vmask, pemb);
    gemm_rowcol<<<dim3(BPAT, 2), 256, 0, stream>>>(pemb, Wd1, bd1, h1, BPAT, 512, D, 1);
    gemm_rowcol<<<dim3(BPAT, 1), 256, 0, stream>>>(h1, Wd2, bd2, h2, BPAT, D, 512, 1);
    gemm_rowcol<<<dim3(BPAT, 4), 256, 0, stream>>>(h2, Wd3, bd3, (float*)d_out, BPAT, 1000, D, 0);
}